// Round 16
// baseline (165.124 us; speedup 1.0000x reference)
//
#include <hip/hip_runtime.h>
#include <hip/hip_bf16.h>

#define NN 10000     // nodes
#define NE 640000    // edges
#define NG 64        // graphs
#define NF 128       // feature dim (both layers)
#define NC 10        // classes
#define TMR 16       // gemm row tile
#define TKC 32       // gemm k chunk
#define NB 250       // dst buckets (40 nodes each)
#define BSZ 40       // nodes per bucket
#define G1 512       // blocks in hist/bucket passes (2 blocks/CU)
#define ECHUNK 1250  // edges per block (G1*ECHUNK == NE)
#define CSRCAP 3072  // k_csr LDS staging capacity (bucket mean 2560, sd ~51)

// ---------------- ws layout (bytes) ----------------
// 0        coff  (10001 int)        40016
// 40016    btot  (250 int)          1024
// 41040    dinv  (10000 f32)        40000
// 81040    csrc  (640000 ushort)    1280000
// 1361040  Gb1   (10000*128 bf16)   2560000  [bh (512KB) aliases: dead pre-gemm1]
// 3921040  Gb2   (10000*128 bf16)   2560000  [ebuf (2.56MB) aliases: dead pre-gathmm]
// 6481040  bufB  (10000*128 f32)    5120000
// total ~11.6 MB; zero global atomics -> no pre-zeroing needed
//
// Math: out[i] = relu( dinv[i]*(sum_{j->i} g[j] + g[i]) + b ), g = dinv*h
// folded into GEMM epilogues. G bf16 (256B row). R16: gather1+gemm2 fused
// (k_gathmm: 16 nodes/block, h kept in LDS transposed) -- removes the H
// round-trip; k_csr stages its bucket in LDS (sequential csrc write).

__device__ __forceinline__ unsigned short f2bf(float f) {   // RNE
    unsigned int u = __float_as_uint(f);
    return (unsigned short)((u + 0x7FFF + ((u >> 16) & 1)) >> 16);
}
__device__ __forceinline__ float bf_lo(unsigned int p) {
    return __uint_as_float(p << 16);
}
__device__ __forceinline__ float bf_hi(unsigned int p) {
    return __uint_as_float(p & 0xFFFF0000u);
}

// In-block exclusive scan of btot[0..NB) over 256 threads -> bbs[] (LDS).
__device__ __forceinline__ void scan_btot(const int* __restrict__ btot,
                                          int* bbs, int* vv, int* wsum) {
    int tid = threadIdx.x, lane = tid & 63, wv = tid >> 6;
    int v = (tid < NB) ? btot[tid] : 0;
    vv[tid] = v;
    int p = v;
    for (int o = 1; o < 64; o <<= 1) {
        int t = __shfl_up(p, o, 64);
        if (lane >= o) p += t;
    }
    if (lane == 63) wsum[wv] = p;
    __syncthreads();
    int off = 0;
#pragma unroll
    for (int j = 0; j < 4; ++j) if (j < wv) off += wsum[j];
    bbs[tid] = p + off - v;              // exclusive prefix
    __syncthreads();
}

// Wave-uniform detection of int64 vs int32 index buffers.
__device__ __forceinline__ int detect64(const int* w, long span) {
    int lane = threadIdx.x & 63;
    long e = (long)lane * (span - 1) / 63;
    return (__ballot(w[2 * e + 1] != 0) == 0ULL) ? 1 : 0;
}

__device__ __forceinline__ int ld_idx(const void* p, long i, int is64) {
    return is64 ? (int)((const long long*)p)[i] : ((const int*)p)[i];
}

// Pass A: per-block bucket histogram, stored bucket-major: bh[b*G1 + g].
__global__ __launch_bounds__(256) void k_hist(const void* __restrict__ ei,
                                              int* __restrict__ bh) {
    int is64 = detect64((const int*)ei, NE);
    __shared__ int hist[256];
    int tid = threadIdx.x;
    hist[tid] = 0;
    __syncthreads();
    int e0 = blockIdx.x * ECHUNK, e1 = min(NE, e0 + ECHUNK);
    for (int e = e0 + tid; e < e1; e += 256) {
        int dst = ld_idx(ei, (long)NE + e, is64);
        atomicAdd(&hist[dst / BSZ], 1);
    }
    __syncthreads();
    bh[tid * G1 + blockIdx.x] = hist[tid];
}

// Pass B: per-bucket exclusive prefix over the G1 group counts (63 blocks).
__global__ __launch_bounds__(256) void k_bscan1(int* __restrict__ bh,
                                                int* __restrict__ btot) {
    int w = blockIdx.x * 4 + (threadIdx.x >> 6);
    if (w >= NB) return;
    int lane = threadIdx.x & 63;
    int base = w * G1 + lane * 8;
    int vals[8];
    int lsum = 0;
#pragma unroll
    for (int i = 0; i < 8; ++i) { vals[i] = bh[base + i]; lsum += vals[i]; }
    int pref = lsum;
    for (int o = 1; o < 64; o <<= 1) {
        int t = __shfl_up(pref, o, 64);
        if (lane >= o) pref += t;
    }
    int run = pref - lsum;                  // exclusive
#pragma unroll
    for (int i = 0; i < 8; ++i) { int v = vals[i]; bh[base + i] = run; run += v; }
    if (lane == 63) btot[w] = run;
}

// Pass C: scatter edges to bucket regions, packed (ldst<<14)|src.
__global__ __launch_bounds__(256) void k_bucket(const void* __restrict__ ei,
                                                const int* __restrict__ bh,
                                                const int* __restrict__ btot,
                                                int* __restrict__ ebuf) {
    int is64 = detect64((const int*)ei, NE);
    __shared__ int bbs[256], vv[256], wsum[4];
    __shared__ int cur[256];
    int tid = threadIdx.x;
    scan_btot(btot, bbs, vv, wsum);
    if (tid < NB) cur[tid] = bh[tid * G1 + blockIdx.x] + bbs[tid];
    __syncthreads();
    int e0 = blockIdx.x * ECHUNK, e1 = min(NE, e0 + ECHUNK);
    for (int e = e0 + tid; e < e1; e += 256) {
        int dst = ld_idx(ei, (long)NE + e, is64);
        int src = ld_idx(ei, (long)e, is64);
        int b = dst / BSZ;
        int p = atomicAdd(&cur[b], 1);
        ebuf[p] = ((dst - b * BSZ) << 14) | src;
    }
}

// Pass D: one block per bucket. Stage the bucket in LDS (1 global read),
// count/scan 40 dsts -> coff + dinv, stable-partition in LDS, then write
// csrc SEQUENTIALLY (coalesced full-line ushort stream). Fallback to the
// two-pass global path if a bucket exceeds CSRCAP (10 sigma; shouldn't).
__global__ __launch_bounds__(256) void k_csr(const int* __restrict__ ebuf,
                                             const int* __restrict__ btot,
                                             int* __restrict__ coff,
                                             float* __restrict__ dinv,
                                             unsigned short* __restrict__ csrc) {
    __shared__ int bbs[256], vv[256], wsum[4];
    __shared__ int s[CSRCAP];            // 12 KB
    __shared__ unsigned short t[CSRCAP]; // 6 KB
    __shared__ int dcount[BSZ];
    __shared__ int dstart[BSZ];
    __shared__ int cur[BSZ];
    int b = blockIdx.x, tid = threadIdx.x;
    scan_btot(btot, bbs, vv, wsum);
    int base = bbs[b], cnt = vv[b], end = base + cnt;
    if (tid < BSZ) dcount[tid] = 0;
    __syncthreads();
    bool lds = (cnt <= CSRCAP);
    if (lds) {
        for (int i = tid; i < cnt; i += 256) s[i] = ebuf[base + i];
        __syncthreads();
        for (int i = tid; i < cnt; i += 256)
            atomicAdd(&dcount[s[i] >> 14], 1);
    } else {
        for (int i = base + tid; i < end; i += 256)
            atomicAdd(&dcount[ebuf[i] >> 14], 1);
    }
    __syncthreads();
    if (tid == 0) {
        int run = 0;
        for (int i = 0; i < BSZ; ++i) {
            dstart[i] = run;
            cur[i] = (lds ? 0 : base) + run;
            run += dcount[i];
        }
    }
    __syncthreads();
    if (tid < BSZ) {
        coff[b * BSZ + tid] = base + dstart[tid];
        dinv[b * BSZ + tid] = rsqrtf((float)dcount[tid] + 1.0f);
    }
    if (b == NB - 1 && tid == 0) coff[NN] = NE;
    __syncthreads();
    if (lds) {
        for (int i = tid; i < cnt; i += 256) {
            int pk = s[i];
            int p = atomicAdd(&cur[pk >> 14], 1);
            t[p] = (unsigned short)(pk & 16383);
        }
        __syncthreads();
        for (int i = tid; i < cnt; i += 256) csrc[base + i] = t[i];
    } else {
        for (int i = base + tid; i < end; i += 256) {
            int pk = ebuf[i];
            int p = atomicAdd(&cur[pk >> 14], 1);
            csrc[p] = (unsigned short)(pk & 16383);
        }
    }
}

// Y(bf16) = (X @ W) * dinv[row]. 625 blocks x (16 rows x 128 cols).
__global__ __launch_bounds__(256) void k_gemm(const float* __restrict__ X,
                                              const float* __restrict__ W,
                                              const float* __restrict__ dinv,
                                              unsigned short* __restrict__ Y,
                                              int nrows) {
    __shared__ float sX[TKC * 20];
    __shared__ float sW[32 * 132];
    int tid = threadIdx.x;
    int rg = tid & 7;
    int cg = tid >> 3;
    int m0 = blockIdx.x * TMR;
    float acc[2][4] = {{0.f}};
    for (int kc = 0; kc < NF / TKC; ++kc) {
        int k0 = kc * TKC;
        if (tid < 128) {
            int row = tid >> 3, kq = tid & 7;
            int mm = m0 + row; if (mm > nrows - 1) mm = nrows - 1;
            float4 v = *(const float4*)(X + (size_t)mm * NF + k0 + kq * 4);
            sX[(kq * 4 + 0) * 20 + row] = v.x;
            sX[(kq * 4 + 1) * 20 + row] = v.y;
            sX[(kq * 4 + 2) * 20 + row] = v.z;
            sX[(kq * 4 + 3) * 20 + row] = v.w;
        }
#pragma unroll
        for (int j = 0; j < 4; ++j) {
            int idx = tid + 256 * j;
            int k = idx >> 5, cq = idx & 31;
            float4 v = *(const float4*)(W + (size_t)(k0 + k) * NF + cq * 4);
            *(float4*)(sW + cq * 132 + k * 4) = v;
        }
        __syncthreads();
#pragma unroll 8
        for (int k = 0; k < TKC; ++k) {
            float2 xf = *(const float2*)(sX + k * 20 + rg * 2);
            float4 wf = *(const float4*)(sW + cg * 132 + k * 4);
            acc[0][0] = fmaf(xf.x, wf.x, acc[0][0]);
            acc[0][1] = fmaf(xf.x, wf.y, acc[0][1]);
            acc[0][2] = fmaf(xf.x, wf.z, acc[0][2]);
            acc[0][3] = fmaf(xf.x, wf.w, acc[0][3]);
            acc[1][0] = fmaf(xf.y, wf.x, acc[1][0]);
            acc[1][1] = fmaf(xf.y, wf.y, acc[1][1]);
            acc[1][2] = fmaf(xf.y, wf.z, acc[1][2]);
            acc[1][3] = fmaf(xf.y, wf.w, acc[1][3]);
        }
        __syncthreads();
    }
#pragma unroll
    for (int r = 0; r < 2; ++r) {
        int m = m0 + rg * 2 + r;
        if (m < nrows) {
            float ds = dinv[m];
            ushort4 h;
            h.x = f2bf(acc[r][0] * ds);
            h.y = f2bf(acc[r][1] * ds);
            h.z = f2bf(acc[r][2] * ds);
            h.w = f2bf(acc[r][3] * ds);
            *(ushort4*)(Y + (size_t)m * NF + cg * 4) = h;
        }
    }
}

// FUSED gather(layer1) + gemm(layer2): block = 16 nodes (625 blocks).
// Phase 1: each wave gathers 4 nodes (quarter-wave uint4, 4-deep unroll),
// computes h = relu(dinv*(agg+self)+b1), writes h TRANSPOSED to LDS.
// Phase 2: 16x128x128 register-tiled gemm from LDS -> Gb2 = bf16(dinv*(h@W2)).
// Accumulation order identical to the unfused R15 pair -> bit-identical.
__global__ __launch_bounds__(256) void k_gathmm(const unsigned short* __restrict__ G,
                                                const int* __restrict__ off,
                                                const unsigned short* __restrict__ csrc,
                                                const float* __restrict__ dinv,
                                                const float* __restrict__ b1,
                                                const float* __restrict__ W2,
                                                unsigned short* __restrict__ Gb2) {
    __shared__ float sXT[NF * 18];       // h transposed [k][m], stride 18, 9.2 KB
    __shared__ float sW[32 * 132];       // 16.9 KB
    int tid = threadIdx.x;
    int wid = tid >> 6, lane = tid & 63;
    int q = lane >> 4, f = lane & 15;
    int m0 = blockIdx.x * TMR;
    // ---- phase 1: gather 4 nodes per wave ----
    for (int tnode = 0; tnode < 4; ++tnode) {
        int mloc = wid * 4 + tnode;
        int n = m0 + mloc;
        int beg = off[n], end = off[n + 1];
        float din = dinv[n];
        float a0 = 0.f, a1 = 0.f, a2 = 0.f, a3 = 0.f;
        float a4 = 0.f, a5 = 0.f, a6 = 0.f, a7 = 0.f;
        int e = beg + q;
        for (; e + 12 < end; e += 16) {
            int s0 = csrc[e];
            int s1 = csrc[e + 4];
            int s2 = csrc[e + 8];
            int s3 = csrc[e + 12];
            uint4 p0 = ((const uint4*)(G + (size_t)s0 * NF))[f];
            uint4 p1 = ((const uint4*)(G + (size_t)s1 * NF))[f];
            uint4 p2 = ((const uint4*)(G + (size_t)s2 * NF))[f];
            uint4 p3 = ((const uint4*)(G + (size_t)s3 * NF))[f];
            a0 += bf_lo(p0.x); a1 += bf_hi(p0.x); a2 += bf_lo(p0.y); a3 += bf_hi(p0.y);
            a4 += bf_lo(p0.z); a5 += bf_hi(p0.z); a6 += bf_lo(p0.w); a7 += bf_hi(p0.w);
            a0 += bf_lo(p1.x); a1 += bf_hi(p1.x); a2 += bf_lo(p1.y); a3 += bf_hi(p1.y);
            a4 += bf_lo(p1.z); a5 += bf_hi(p1.z); a6 += bf_lo(p1.w); a7 += bf_hi(p1.w);
            a0 += bf_lo(p2.x); a1 += bf_hi(p2.x); a2 += bf_lo(p2.y); a3 += bf_hi(p2.y);
            a4 += bf_lo(p2.z); a5 += bf_hi(p2.z); a6 += bf_lo(p2.w); a7 += bf_hi(p2.w);
            a0 += bf_lo(p3.x); a1 += bf_hi(p3.x); a2 += bf_lo(p3.y); a3 += bf_hi(p3.y);
            a4 += bf_lo(p3.z); a5 += bf_hi(p3.z); a6 += bf_lo(p3.w); a7 += bf_hi(p3.w);
        }
        for (; e < end; e += 4) {
            int s = csrc[e];
            uint4 p = ((const uint4*)(G + (size_t)s * NF))[f];
            a0 += bf_lo(p.x); a1 += bf_hi(p.x); a2 += bf_lo(p.y); a3 += bf_hi(p.y);
            a4 += bf_lo(p.z); a5 += bf_hi(p.z); a6 += bf_lo(p.w); a7 += bf_hi(p.w);
        }
        a0 += __shfl_xor(a0, 16); a1 += __shfl_xor(a1, 16);
        a2 += __shfl_xor(a2, 16); a3 += __shfl_xor(a3, 16);
        a4 += __shfl_xor(a4, 16); a5 += __shfl_xor(a5, 16);
        a6 += __shfl_xor(a6, 16); a7 += __shfl_xor(a7, 16);
        a0 += __shfl_xor(a0, 32); a1 += __shfl_xor(a1, 32);
        a2 += __shfl_xor(a2, 32); a3 += __shfl_xor(a3, 32);
        a4 += __shfl_xor(a4, 32); a5 += __shfl_xor(a5, 32);
        a6 += __shfl_xor(a6, 32); a7 += __shfl_xor(a7, 32);
        if (q == 0) {
            uint4 sp = ((const uint4*)(G + (size_t)n * NF))[f];
            float4 c0 = ((const float4*)b1)[2 * f];
            float4 c1 = ((const float4*)b1)[2 * f + 1];
            float h0 = fmaxf(fmaf(din, a0 + bf_lo(sp.x), c0.x), 0.f);
            float h1 = fmaxf(fmaf(din, a1 + bf_hi(sp.x), c0.y), 0.f);
            float h2 = fmaxf(fmaf(din, a2 + bf_lo(sp.y), c0.z), 0.f);
            float h3 = fmaxf(fmaf(din, a3 + bf_hi(sp.y), c0.w), 0.f);
            float h4 = fmaxf(fmaf(din, a4 + bf_lo(sp.z), c1.x), 0.f);
            float h5 = fmaxf(fmaf(din, a5 + bf_hi(sp.z), c1.y), 0.f);
            float h6 = fmaxf(fmaf(din, a6 + bf_lo(sp.w), c1.z), 0.f);
            float h7 = fmaxf(fmaf(din, a7 + bf_hi(sp.w), c1.w), 0.f);
            int kb = f * 8;
            sXT[(kb + 0) * 18 + mloc] = h0;
            sXT[(kb + 1) * 18 + mloc] = h1;
            sXT[(kb + 2) * 18 + mloc] = h2;
            sXT[(kb + 3) * 18 + mloc] = h3;
            sXT[(kb + 4) * 18 + mloc] = h4;
            sXT[(kb + 5) * 18 + mloc] = h5;
            sXT[(kb + 6) * 18 + mloc] = h6;
            sXT[(kb + 7) * 18 + mloc] = h7;
        }
    }
    __syncthreads();
    // ---- phase 2: 16x128 gemm (identical order to k_gemm) ----
    int rg = tid & 7;
    int cg = tid >> 3;
    float acc[2][4] = {{0.f}};
    for (int kc = 0; kc < NF / TKC; ++kc) {
        int k0 = kc * TKC;
#pragma unroll
        for (int j = 0; j < 4; ++j) {
            int idx = tid + 256 * j;
            int k = idx >> 5, cq = idx & 31;
            float4 v = *(const float4*)(W2 + (size_t)(k0 + k) * NF + cq * 4);
            *(float4*)(sW + cq * 132 + k * 4) = v;
        }
        __syncthreads();
#pragma unroll 8
        for (int k = 0; k < TKC; ++k) {
            float2 xf = *(const float2*)(sXT + (k0 + k) * 18 + rg * 2);
            float4 wf = *(const float4*)(sW + cg * 132 + k * 4);
            acc[0][0] = fmaf(xf.x, wf.x, acc[0][0]);
            acc[0][1] = fmaf(xf.x, wf.y, acc[0][1]);
            acc[0][2] = fmaf(xf.x, wf.z, acc[0][2]);
            acc[0][3] = fmaf(xf.x, wf.w, acc[0][3]);
            acc[1][0] = fmaf(xf.y, wf.x, acc[1][0]);
            acc[1][1] = fmaf(xf.y, wf.y, acc[1][1]);
            acc[1][2] = fmaf(xf.y, wf.z, acc[1][2]);
            acc[1][3] = fmaf(xf.y, wf.w, acc[1][3]);
        }
        __syncthreads();
    }
#pragma unroll
    for (int r = 0; r < 2; ++r) {
        int m = m0 + rg * 2 + r;
        float ds = dinv[m];
        ushort4 h;
        h.x = f2bf(acc[r][0] * ds);
        h.y = f2bf(acc[r][1] * ds);
        h.z = f2bf(acc[r][2] * ds);
        h.w = f2bf(acc[r][3] * ds);
        *(ushort4*)(Gb2 + (size_t)m * NF + cg * 4) = h;
    }
}

// OUT[n] = relu( dinv[n]*( sum_e G[csrc[e]] + G[n] ) + bias ), G bf16.
__global__ __launch_bounds__(256) void k_gather(const unsigned short* __restrict__ G,
                                                const int* __restrict__ off,
                                                const unsigned short* __restrict__ csrc,
                                                const float* __restrict__ dinv,
                                                const float* __restrict__ bias,
                                                float* __restrict__ OUT) {
    int wid = threadIdx.x >> 6, lane = threadIdx.x & 63;
    int q = lane >> 4, f = lane & 15;
    int n = blockIdx.x * 4 + wid;
    if (n >= NN) return;
    int beg = off[n], end = off[n + 1];
    float din = dinv[n];
    float a0 = 0.f, a1 = 0.f, a2 = 0.f, a3 = 0.f;
    float a4 = 0.f, a5 = 0.f, a6 = 0.f, a7 = 0.f;
    int e = beg + q;
    for (; e + 12 < end; e += 16) {
        int s0 = csrc[e];
        int s1 = csrc[e + 4];
        int s2 = csrc[e + 8];
        int s3 = csrc[e + 12];
        uint4 p0 = ((const uint4*)(G + (size_t)s0 * NF))[f];
        uint4 p1 = ((const uint4*)(G + (size_t)s1 * NF))[f];
        uint4 p2 = ((const uint4*)(G + (size_t)s2 * NF))[f];
        uint4 p3 = ((const uint4*)(G + (size_t)s3 * NF))[f];
        a0 += bf_lo(p0.x); a1 += bf_hi(p0.x); a2 += bf_lo(p0.y); a3 += bf_hi(p0.y);
        a4 += bf_lo(p0.z); a5 += bf_hi(p0.z); a6 += bf_lo(p0.w); a7 += bf_hi(p0.w);
        a0 += bf_lo(p1.x); a1 += bf_hi(p1.x); a2 += bf_lo(p1.y); a3 += bf_hi(p1.y);
        a4 += bf_lo(p1.z); a5 += bf_hi(p1.z); a6 += bf_lo(p1.w); a7 += bf_hi(p1.w);
        a0 += bf_lo(p2.x); a1 += bf_hi(p2.x); a2 += bf_lo(p2.y); a3 += bf_hi(p2.y);
        a4 += bf_lo(p2.z); a5 += bf_hi(p2.z); a6 += bf_lo(p2.w); a7 += bf_hi(p2.w);
        a0 += bf_lo(p3.x); a1 += bf_hi(p3.x); a2 += bf_lo(p3.y); a3 += bf_hi(p3.y);
        a4 += bf_lo(p3.z); a5 += bf_hi(p3.z); a6 += bf_lo(p3.w); a7 += bf_hi(p3.w);
    }
    for (; e < end; e += 4) {
        int s = csrc[e];
        uint4 p = ((const uint4*)(G + (size_t)s * NF))[f];
        a0 += bf_lo(p.x); a1 += bf_hi(p.x); a2 += bf_lo(p.y); a3 += bf_hi(p.y);
        a4 += bf_lo(p.z); a5 += bf_hi(p.z); a6 += bf_lo(p.w); a7 += bf_hi(p.w);
    }
    a0 += __shfl_xor(a0, 16); a1 += __shfl_xor(a1, 16);
    a2 += __shfl_xor(a2, 16); a3 += __shfl_xor(a3, 16);
    a4 += __shfl_xor(a4, 16); a5 += __shfl_xor(a5, 16);
    a6 += __shfl_xor(a6, 16); a7 += __shfl_xor(a7, 16);
    a0 += __shfl_xor(a0, 32); a1 += __shfl_xor(a1, 32);
    a2 += __shfl_xor(a2, 32); a3 += __shfl_xor(a3, 32);
    a4 += __shfl_xor(a4, 32); a5 += __shfl_xor(a5, 32);
    a6 += __shfl_xor(a6, 32); a7 += __shfl_xor(a7, 32);
    if (q == 0) {
        uint4 sp = ((const uint4*)(G + (size_t)n * NF))[f];
        float4 b0 = ((const float4*)bias)[2 * f];
        float4 b1 = ((const float4*)bias)[2 * f + 1];
        float4 o0, o1;
        o0.x = fmaxf(fmaf(din, a0 + bf_lo(sp.x), b0.x), 0.f);
        o0.y = fmaxf(fmaf(din, a1 + bf_hi(sp.x), b0.y), 0.f);
        o0.z = fmaxf(fmaf(din, a2 + bf_lo(sp.y), b0.z), 0.f);
        o0.w = fmaxf(fmaf(din, a3 + bf_hi(sp.y), b0.w), 0.f);
        o1.x = fmaxf(fmaf(din, a4 + bf_lo(sp.z), b1.x), 0.f);
        o1.y = fmaxf(fmaf(din, a5 + bf_hi(sp.z), b1.y), 0.f);
        o1.z = fmaxf(fmaf(din, a6 + bf_lo(sp.w), b1.z), 0.f);
        o1.w = fmaxf(fmaf(din, a7 + bf_hi(sp.w), b1.w), 0.f);
        ((float4*)(OUT + (size_t)n * NF))[2 * f] = o0;
        ((float4*)(OUT + (size_t)n * NF))[2 * f + 1] = o1;
    }
}

// Fused global-mean-pool + final linear (batch is sorted -> contiguous ranges).
__global__ __launch_bounds__(256) void k_poolfin(const float* __restrict__ H,
                                                 const void* __restrict__ batch,
                                                 const float* __restrict__ Wl,
                                                 const float* __restrict__ bl,
                                                 float* __restrict__ out) {
    int is64 = detect64((const int*)batch, NN / 2);
    __shared__ int sb[2];
    __shared__ float4 part[256];
    __shared__ float pooled[NF];
    int g = blockIdx.x;
    int tid = threadIdx.x;
    if (tid < 2) {
        int target = g + tid;                 // lower_bound(batch, target)
        int lo = 0, hi = NN;
        while (lo < hi) {
            int mid = (lo + hi) >> 1;
            if (ld_idx(batch, mid, is64) < target) lo = mid + 1; else hi = mid;
        }
        sb[tid] = lo;
    }
    __syncthreads();
    int beg = sb[0], end = sb[1];
    int c4 = tid & 31, r = tid >> 5;
    float4 acc = make_float4(0.f, 0.f, 0.f, 0.f);
    for (int n = beg + r; n < end; n += 8) {
        float4 v = ((const float4*)(H + (size_t)n * NF))[c4];
        acc.x += v.x; acc.y += v.y; acc.z += v.z; acc.w += v.w;
    }
    part[tid] = acc;
    __syncthreads();
    if (tid < 32) {
        float4 s = part[tid];
#pragma unroll
        for (int j = 1; j < 8; j++) {
            float4 p = part[tid + 32 * j];
            s.x += p.x; s.y += p.y; s.z += p.z; s.w += p.w;
        }
        float ic = 1.0f / fmaxf((float)(end - beg), 1.0f);
        pooled[tid * 4 + 0] = s.x * ic;
        pooled[tid * 4 + 1] = s.y * ic;
        pooled[tid * 4 + 2] = s.z * ic;
        pooled[tid * 4 + 3] = s.w * ic;
    }
    __syncthreads();
    if (tid < NC) {
        float a = bl[tid];
#pragma unroll 8
        for (int k = 0; k < NF; k++)
            a = fmaf(pooled[k], Wl[k * NC + tid], a);
        out[g * NC + tid] = a;
    }
}

extern "C" void kernel_launch(void* const* d_in, const int* in_sizes, int n_in,
                              void* d_out, int out_size, void* d_ws, size_t ws_size,
                              hipStream_t stream) {
    const float* x  = (const float*)d_in[0];
    const void*  ei = d_in[1];
    const void*  bt = d_in[2];
    const float* W1 = (const float*)d_in[3];
    const float* b1 = (const float*)d_in[4];
    const float* W2 = (const float*)d_in[5];
    const float* b2 = (const float*)d_in[6];
    const float* Wl = (const float*)d_in[7];
    const float* bl = (const float*)d_in[8];

    char* ws = (char*)d_ws;
    int*            coff  = (int*)(ws + 0);
    int*            btot  = (int*)(ws + 40016);
    float*          dinv  = (float*)(ws + 41040);
    unsigned short* csrc  = (unsigned short*)(ws + 81040);
    unsigned short* Gb1   = (unsigned short*)(ws + 1361040); // bf16 G1 (2.56MB)
    unsigned short* Gb2   = (unsigned short*)(ws + 3921040); // bf16 G2 (2.56MB)
    float*          bufB  = (float*)(ws + 6481040);          // f32 H2 (5.12MB)
    int*            bh    = (int*)(ws + 1361040);  // 512KB scratch, dead pre-gemm1
    int*            ebuf  = (int*)(ws + 3921040);  // 2.56MB scratch, dead pre-gathmm

    k_hist  <<<G1, 256, 0, stream>>>(ei, bh);
    k_bscan1<<<(NB + 3) / 4, 256, 0, stream>>>(bh, btot);
    k_bucket<<<G1, 256, 0, stream>>>(ei, bh, btot, ebuf);
    k_csr   <<<NB, 256, 0, stream>>>(ebuf, btot, coff, dinv, csrc);

    k_gemm  <<<(NN + TMR - 1) / TMR, 256, 0, stream>>>(x, W1, dinv, Gb1, NN);
    k_gathmm<<<NN / TMR, 256, 0, stream>>>(Gb1, coff, csrc, dinv, b1, W2, Gb2);
    k_gather<<<(NN + 3) / 4, 256, 0, stream>>>(Gb2, coff, csrc, dinv, b2, bufB);

    k_poolfin<<<NG, 256, 0, stream>>>(bufB, bt, Wl, bl, (float*)d_out);
}

// Round 17
// 164.358 us; speedup vs baseline: 1.0047x; 1.0047x over previous
//
#include <hip/hip_runtime.h>
#include <hip/hip_bf16.h>

#define NN 10000     // nodes
#define NE 640000    // edges
#define NG 64        // graphs
#define NF 128       // feature dim (both layers)
#define NC 10        // classes
#define TMR 16       // gemm row tile (625 blocks -> 2.4/CU)
#define TKC 32       // gemm k chunk
#define NB 250       // dst buckets (40 nodes each)
#define BSZ 40       // nodes per bucket
#define G1 512       // blocks in hist/bucket passes (2 blocks/CU)
#define ECHUNK 1250  // edges per block (G1*ECHUNK == NE)
#define CSRCAP 3072  // k_csr LDS staging capacity (bucket mean 2560, sd ~51)

// ---------------- ws layout (bytes) ----------------
// 0        coff  (10001 int)        40016
// 40016    btot  (250 int)          1024
// 41040    dinv  (10000 f32)        40000
// 81040    csrc  (640000 ushort)    1280000
// 1361040  Gb    (10000*128 bf16)   2560000  [bh (512KB) aliases: dead pre-gemm1]
// 3921040  bufB  (10000*128 f32)    5120000  [ebuf (2.56MB) aliases: dead pre-gath1]
// total ~9.0 MB; zero global atomics -> no pre-zeroing needed
//
// Math: out[i] = relu( dinv[i]*(sum_{j->i} g[j] + g[i]) + b ), g = dinv*h
// folded into the GEMM epilogue. G bf16 (256B row = 4 lines/edge).
// R17 = R15 structure (unfused -- R16 proved the gather needs max wave-count
// for MSHR parallelism; fusion to 2.4 blocks/CU regressed) + R16's k_csr
// (LDS-staged bucket, sequential coalesced csrc write).

__device__ __forceinline__ unsigned short f2bf(float f) {   // RNE
    unsigned int u = __float_as_uint(f);
    return (unsigned short)((u + 0x7FFF + ((u >> 16) & 1)) >> 16);
}
__device__ __forceinline__ float bf_lo(unsigned int p) {
    return __uint_as_float(p << 16);
}
__device__ __forceinline__ float bf_hi(unsigned int p) {
    return __uint_as_float(p & 0xFFFF0000u);
}

// In-block exclusive scan of btot[0..NB) over 256 threads -> bbs[] (LDS).
__device__ __forceinline__ void scan_btot(const int* __restrict__ btot,
                                          int* bbs, int* vv, int* wsum) {
    int tid = threadIdx.x, lane = tid & 63, wv = tid >> 6;
    int v = (tid < NB) ? btot[tid] : 0;
    vv[tid] = v;
    int p = v;
    for (int o = 1; o < 64; o <<= 1) {
        int t = __shfl_up(p, o, 64);
        if (lane >= o) p += t;
    }
    if (lane == 63) wsum[wv] = p;
    __syncthreads();
    int off = 0;
#pragma unroll
    for (int j = 0; j < 4; ++j) if (j < wv) off += wsum[j];
    bbs[tid] = p + off - v;              // exclusive prefix
    __syncthreads();
}

// Wave-uniform detection of int64 vs int32 index buffers. For little-endian
// int64, every odd 32-bit word is the (always-zero here) high half.
__device__ __forceinline__ int detect64(const int* w, long span) {
    int lane = threadIdx.x & 63;
    long e = (long)lane * (span - 1) / 63;
    return (__ballot(w[2 * e + 1] != 0) == 0ULL) ? 1 : 0;
}

__device__ __forceinline__ int ld_idx(const void* p, long i, int is64) {
    return is64 ? (int)((const long long*)p)[i] : ((const int*)p)[i];
}

// Pass A: per-block bucket histogram, stored bucket-major: bh[b*G1 + g].
__global__ __launch_bounds__(256) void k_hist(const void* __restrict__ ei,
                                              int* __restrict__ bh) {
    int is64 = detect64((const int*)ei, NE);
    __shared__ int hist[256];
    int tid = threadIdx.x;
    hist[tid] = 0;
    __syncthreads();
    int e0 = blockIdx.x * ECHUNK, e1 = min(NE, e0 + ECHUNK);
    for (int e = e0 + tid; e < e1; e += 256) {
        int dst = ld_idx(ei, (long)NE + e, is64);
        atomicAdd(&hist[dst / BSZ], 1);
    }
    __syncthreads();
    bh[tid * G1 + blockIdx.x] = hist[tid];
}

// Pass B: per-bucket exclusive prefix over the G1 group counts (63 blocks).
__global__ __launch_bounds__(256) void k_bscan1(int* __restrict__ bh,
                                                int* __restrict__ btot) {
    int w = blockIdx.x * 4 + (threadIdx.x >> 6);
    if (w >= NB) return;
    int lane = threadIdx.x & 63;
    int base = w * G1 + lane * 8;
    int vals[8];
    int lsum = 0;
#pragma unroll
    for (int i = 0; i < 8; ++i) { vals[i] = bh[base + i]; lsum += vals[i]; }
    int pref = lsum;
    for (int o = 1; o < 64; o <<= 1) {
        int t = __shfl_up(pref, o, 64);
        if (lane >= o) pref += t;
    }
    int run = pref - lsum;                  // exclusive
#pragma unroll
    for (int i = 0; i < 8; ++i) { int v = vals[i]; bh[base + i] = run; run += v; }
    if (lane == 63) btot[w] = run;
}

// Pass C: scatter edges to bucket regions, packed (ldst<<14)|src. Bucket
// bases recomputed in-block from btot; per-(block,bucket) contiguous ranges.
__global__ __launch_bounds__(256) void k_bucket(const void* __restrict__ ei,
                                                const int* __restrict__ bh,
                                                const int* __restrict__ btot,
                                                int* __restrict__ ebuf) {
    int is64 = detect64((const int*)ei, NE);
    __shared__ int bbs[256], vv[256], wsum[4];
    __shared__ int cur[256];
    int tid = threadIdx.x;
    scan_btot(btot, bbs, vv, wsum);
    if (tid < NB) cur[tid] = bh[tid * G1 + blockIdx.x] + bbs[tid];
    __syncthreads();
    int e0 = blockIdx.x * ECHUNK, e1 = min(NE, e0 + ECHUNK);
    for (int e = e0 + tid; e < e1; e += 256) {
        int dst = ld_idx(ei, (long)NE + e, is64);
        int src = ld_idx(ei, (long)e, is64);
        int b = dst / BSZ;
        int p = atomicAdd(&cur[b], 1);
        ebuf[p] = ((dst - b * BSZ) << 14) | src;
    }
}

// Pass D: one block per bucket. Stage the bucket in LDS (1 global read),
// count/scan 40 dsts -> coff + dinv, stable-partition in LDS, then write
// csrc SEQUENTIALLY (coalesced full-line ushort stream). Fallback to the
// two-pass global path if a bucket exceeds CSRCAP (10 sigma; shouldn't).
__global__ __launch_bounds__(256) void k_csr(const int* __restrict__ ebuf,
                                             const int* __restrict__ btot,
                                             int* __restrict__ coff,
                                             float* __restrict__ dinv,
                                             unsigned short* __restrict__ csrc) {
    __shared__ int bbs[256], vv[256], wsum[4];
    __shared__ int s[CSRCAP];            // 12 KB
    __shared__ unsigned short t[CSRCAP]; // 6 KB
    __shared__ int dcount[BSZ];
    __shared__ int dstart[BSZ];
    __shared__ int cur[BSZ];
    int b = blockIdx.x, tid = threadIdx.x;
    scan_btot(btot, bbs, vv, wsum);
    int base = bbs[b], cnt = vv[b], end = base + cnt;
    if (tid < BSZ) dcount[tid] = 0;
    __syncthreads();
    bool lds = (cnt <= CSRCAP);
    if (lds) {
        for (int i = tid; i < cnt; i += 256) s[i] = ebuf[base + i];
        __syncthreads();
        for (int i = tid; i < cnt; i += 256)
            atomicAdd(&dcount[s[i] >> 14], 1);
    } else {
        for (int i = base + tid; i < end; i += 256)
            atomicAdd(&dcount[ebuf[i] >> 14], 1);
    }
    __syncthreads();
    if (tid == 0) {
        int run = 0;
        for (int i = 0; i < BSZ; ++i) {
            dstart[i] = run;
            cur[i] = (lds ? 0 : base) + run;
            run += dcount[i];
        }
    }
    __syncthreads();
    if (tid < BSZ) {
        coff[b * BSZ + tid] = base + dstart[tid];
        dinv[b * BSZ + tid] = rsqrtf((float)dcount[tid] + 1.0f);
    }
    if (b == NB - 1 && tid == 0) coff[NN] = NE;
    __syncthreads();
    if (lds) {
        for (int i = tid; i < cnt; i += 256) {
            int pk = s[i];
            int p = atomicAdd(&cur[pk >> 14], 1);
            t[p] = (unsigned short)(pk & 16383);
        }
        __syncthreads();
        for (int i = tid; i < cnt; i += 256) csrc[base + i] = t[i];
    } else {
        for (int i = base + tid; i < end; i += 256) {
            int pk = ebuf[i];
            int p = atomicAdd(&cur[pk >> 14], 1);
            csrc[p] = (unsigned short)(pk & 16383);
        }
    }
}

// Y(bf16) = (X @ W) * dinv[row]. 625 blocks x (16 rows x 128 cols), 256 thr;
// per-thread 2 rows x 4 cols.
__global__ __launch_bounds__(256) void k_gemm(const float* __restrict__ X,
                                              const float* __restrict__ W,
                                              const float* __restrict__ dinv,
                                              unsigned short* __restrict__ Y,
                                              int nrows) {
    __shared__ float sX[TKC * 20];       // [k][m] stride 20, 2.6 KB
    __shared__ float sW[32 * 132];       // 16.9 KB, 32 col-panels of 4
    int tid = threadIdx.x;
    int rg = tid & 7;                    // rows rg*2, rg*2+1
    int cg = tid >> 3;                   // cols cg*4 .. cg*4+3 (0..31)
    int m0 = blockIdx.x * TMR;
    float acc[2][4] = {{0.f}};
    for (int kc = 0; kc < NF / TKC; ++kc) {
        int k0 = kc * TKC;
        if (tid < 128) {                 // stage X^T (16 rows x 32 k)
            int row = tid >> 3, kq = tid & 7;
            int mm = m0 + row; if (mm > nrows - 1) mm = nrows - 1;
            float4 v = *(const float4*)(X + (size_t)mm * NF + k0 + kq * 4);
            sX[(kq * 4 + 0) * 20 + row] = v.x;
            sX[(kq * 4 + 1) * 20 + row] = v.y;
            sX[(kq * 4 + 2) * 20 + row] = v.z;
            sX[(kq * 4 + 3) * 20 + row] = v.w;
        }
#pragma unroll
        for (int j = 0; j < 4; ++j) {    // stage W panels (4 float4 per thread)
            int idx = tid + 256 * j;
            int k = idx >> 5, cq = idx & 31;
            float4 v = *(const float4*)(W + (size_t)(k0 + k) * NF + cq * 4);
            *(float4*)(sW + cq * 132 + k * 4) = v;
        }
        __syncthreads();
#pragma unroll 8
        for (int k = 0; k < TKC; ++k) {
            float2 xf = *(const float2*)(sX + k * 20 + rg * 2);
            float4 wf = *(const float4*)(sW + cg * 132 + k * 4);
            acc[0][0] = fmaf(xf.x, wf.x, acc[0][0]);
            acc[0][1] = fmaf(xf.x, wf.y, acc[0][1]);
            acc[0][2] = fmaf(xf.x, wf.z, acc[0][2]);
            acc[0][3] = fmaf(xf.x, wf.w, acc[0][3]);
            acc[1][0] = fmaf(xf.y, wf.x, acc[1][0]);
            acc[1][1] = fmaf(xf.y, wf.y, acc[1][1]);
            acc[1][2] = fmaf(xf.y, wf.z, acc[1][2]);
            acc[1][3] = fmaf(xf.y, wf.w, acc[1][3]);
        }
        __syncthreads();
    }
#pragma unroll
    for (int r = 0; r < 2; ++r) {
        int m = m0 + rg * 2 + r;
        if (m < nrows) {
            float ds = dinv[m];
            ushort4 h;
            h.x = f2bf(acc[r][0] * ds);
            h.y = f2bf(acc[r][1] * ds);
            h.z = f2bf(acc[r][2] * ds);
            h.w = f2bf(acc[r][3] * ds);
            *(ushort4*)(Y + (size_t)m * NF + cg * 4) = h;
        }
    }
}

// OUT[n] = relu( dinv[n]*( sum_e G[csrc[e]] + G[n] ) + bias ), G bf16.
// One wave per node; quarter-wave (16 lanes x uint4 = full 256B row) per
// edge -> 4 edges per VMEM instruction; 4-deep unroll; fp32 accumulation.
// 2500 blocks (9.8/CU) -- max wave-count for MSHR parallelism (R16 lesson).
__global__ __launch_bounds__(256) void k_gather(const unsigned short* __restrict__ G,
                                                const int* __restrict__ off,
                                                const unsigned short* __restrict__ csrc,
                                                const float* __restrict__ dinv,
                                                const float* __restrict__ bias,
                                                float* __restrict__ OUT) {
    int wid = threadIdx.x >> 6, lane = threadIdx.x & 63;
    int q = lane >> 4, f = lane & 15;
    int n = blockIdx.x * 4 + wid;
    if (n >= NN) return;
    int beg = off[n], end = off[n + 1];
    float din = dinv[n];
    float a0 = 0.f, a1 = 0.f, a2 = 0.f, a3 = 0.f;
    float a4 = 0.f, a5 = 0.f, a6 = 0.f, a7 = 0.f;
    int e = beg + q;
    for (; e + 12 < end; e += 16) {
        int s0 = csrc[e];
        int s1 = csrc[e + 4];
        int s2 = csrc[e + 8];
        int s3 = csrc[e + 12];
        uint4 p0 = ((const uint4*)(G + (size_t)s0 * NF))[f];
        uint4 p1 = ((const uint4*)(G + (size_t)s1 * NF))[f];
        uint4 p2 = ((const uint4*)(G + (size_t)s2 * NF))[f];
        uint4 p3 = ((const uint4*)(G + (size_t)s3 * NF))[f];
        a0 += bf_lo(p0.x); a1 += bf_hi(p0.x); a2 += bf_lo(p0.y); a3 += bf_hi(p0.y);
        a4 += bf_lo(p0.z); a5 += bf_hi(p0.z); a6 += bf_lo(p0.w); a7 += bf_hi(p0.w);
        a0 += bf_lo(p1.x); a1 += bf_hi(p1.x); a2 += bf_lo(p1.y); a3 += bf_hi(p1.y);
        a4 += bf_lo(p1.z); a5 += bf_hi(p1.z); a6 += bf_lo(p1.w); a7 += bf_hi(p1.w);
        a0 += bf_lo(p2.x); a1 += bf_hi(p2.x); a2 += bf_lo(p2.y); a3 += bf_hi(p2.y);
        a4 += bf_lo(p2.z); a5 += bf_hi(p2.z); a6 += bf_lo(p2.w); a7 += bf_hi(p2.w);
        a0 += bf_lo(p3.x); a1 += bf_hi(p3.x); a2 += bf_lo(p3.y); a3 += bf_hi(p3.y);
        a4 += bf_lo(p3.z); a5 += bf_hi(p3.z); a6 += bf_lo(p3.w); a7 += bf_hi(p3.w);
    }
    for (; e < end; e += 4) {
        int s = csrc[e];
        uint4 p = ((const uint4*)(G + (size_t)s * NF))[f];
        a0 += bf_lo(p.x); a1 += bf_hi(p.x); a2 += bf_lo(p.y); a3 += bf_hi(p.y);
        a4 += bf_lo(p.z); a5 += bf_hi(p.z); a6 += bf_lo(p.w); a7 += bf_hi(p.w);
    }
    a0 += __shfl_xor(a0, 16); a1 += __shfl_xor(a1, 16);
    a2 += __shfl_xor(a2, 16); a3 += __shfl_xor(a3, 16);
    a4 += __shfl_xor(a4, 16); a5 += __shfl_xor(a5, 16);
    a6 += __shfl_xor(a6, 16); a7 += __shfl_xor(a7, 16);
    a0 += __shfl_xor(a0, 32); a1 += __shfl_xor(a1, 32);
    a2 += __shfl_xor(a2, 32); a3 += __shfl_xor(a3, 32);
    a4 += __shfl_xor(a4, 32); a5 += __shfl_xor(a5, 32);
    a6 += __shfl_xor(a6, 32); a7 += __shfl_xor(a7, 32);
    if (q == 0) {
        uint4 sp = ((const uint4*)(G + (size_t)n * NF))[f];
        float4 b0 = ((const float4*)bias)[2 * f];
        float4 b1 = ((const float4*)bias)[2 * f + 1];
        float4 o0, o1;
        o0.x = fmaxf(fmaf(din, a0 + bf_lo(sp.x), b0.x), 0.f);
        o0.y = fmaxf(fmaf(din, a1 + bf_hi(sp.x), b0.y), 0.f);
        o0.z = fmaxf(fmaf(din, a2 + bf_lo(sp.y), b0.z), 0.f);
        o0.w = fmaxf(fmaf(din, a3 + bf_hi(sp.y), b0.w), 0.f);
        o1.x = fmaxf(fmaf(din, a4 + bf_lo(sp.z), b1.x), 0.f);
        o1.y = fmaxf(fmaf(din, a5 + bf_hi(sp.z), b1.y), 0.f);
        o1.z = fmaxf(fmaf(din, a6 + bf_lo(sp.w), b1.z), 0.f);
        o1.w = fmaxf(fmaf(din, a7 + bf_hi(sp.w), b1.w), 0.f);
        ((float4*)(OUT + (size_t)n * NF))[2 * f] = o0;
        ((float4*)(OUT + (size_t)n * NF))[2 * f + 1] = o1;
    }
}

// Fused global-mean-pool + final linear (batch is sorted -> contiguous ranges).
__global__ __launch_bounds__(256) void k_poolfin(const float* __restrict__ H,
                                                 const void* __restrict__ batch,
                                                 const float* __restrict__ Wl,
                                                 const float* __restrict__ bl,
                                                 float* __restrict__ out) {
    int is64 = detect64((const int*)batch, NN / 2);
    __shared__ int sb[2];
    __shared__ float4 part[256];
    __shared__ float pooled[NF];
    int g = blockIdx.x;
    int tid = threadIdx.x;
    if (tid < 2) {
        int target = g + tid;                 // lower_bound(batch, target)
        int lo = 0, hi = NN;
        while (lo < hi) {
            int mid = (lo + hi) >> 1;
            if (ld_idx(batch, mid, is64) < target) lo = mid + 1; else hi = mid;
        }
        sb[tid] = lo;
    }
    __syncthreads();
    int beg = sb[0], end = sb[1];
    int c4 = tid & 31, r = tid >> 5;          // 8 rows in flight
    float4 acc = make_float4(0.f, 0.f, 0.f, 0.f);
    for (int n = beg + r; n < end; n += 8) {
        float4 v = ((const float4*)(H + (size_t)n * NF))[c4];
        acc.x += v.x; acc.y += v.y; acc.z += v.z; acc.w += v.w;
    }
    part[tid] = acc;
    __syncthreads();
    if (tid < 32) {
        float4 s = part[tid];
#pragma unroll
        for (int j = 1; j < 8; j++) {
            float4 p = part[tid + 32 * j];
            s.x += p.x; s.y += p.y; s.z += p.z; s.w += p.w;
        }
        float ic = 1.0f / fmaxf((float)(end - beg), 1.0f);
        pooled[tid * 4 + 0] = s.x * ic;
        pooled[tid * 4 + 1] = s.y * ic;
        pooled[tid * 4 + 2] = s.z * ic;
        pooled[tid * 4 + 3] = s.w * ic;
    }
    __syncthreads();
    if (tid < NC) {
        float a = bl[tid];
#pragma unroll 8
        for (int k = 0; k < NF; k++)
            a = fmaf(pooled[k], Wl[k * NC + tid], a);
        out[g * NC + tid] = a;
    }
}

extern "C" void kernel_launch(void* const* d_in, const int* in_sizes, int n_in,
                              void* d_out, int out_size, void* d_ws, size_t ws_size,
                              hipStream_t stream) {
    const float* x  = (const float*)d_in[0];
    const void*  ei = d_in[1];
    const void*  bt = d_in[2];
    const float* W1 = (const float*)d_in[3];
    const float* b1 = (const float*)d_in[4];
    const float* W2 = (const float*)d_in[5];
    const float* b2 = (const float*)d_in[6];
    const float* Wl = (const float*)d_in[7];
    const float* bl = (const float*)d_in[8];

    char* ws = (char*)d_ws;
    int*            coff  = (int*)(ws + 0);
    int*            btot  = (int*)(ws + 40016);
    float*          dinv  = (float*)(ws + 41040);
    unsigned short* csrc  = (unsigned short*)(ws + 81040);
    unsigned short* Gb    = (unsigned short*)(ws + 1361040); // bf16 G (2.56MB)
    float*          bufB  = (float*)(ws + 3921040);          // f32 H (5.12MB)
    int*            bh    = (int*)(ws + 1361040);  // 512KB scratch, dead pre-gemm1
    int*            ebuf  = (int*)(ws + 3921040);  // 2.56MB scratch, dead pre-gather1

    k_hist  <<<G1, 256, 0, stream>>>(ei, bh);
    k_bscan1<<<(NB + 3) / 4, 256, 0, stream>>>(bh, btot);
    k_bucket<<<G1, 256, 0, stream>>>(ei, bh, btot, ebuf);
    k_csr   <<<NB, 256, 0, stream>>>(ebuf, btot, coff, dinv, csrc);

    k_gemm<<<(NN + TMR - 1) / TMR, 256, 0, stream>>>(x, W1, dinv, Gb, NN);
    k_gather<<<(NN + 3) / 4, 256, 0, stream>>>(Gb, coff, csrc, dinv, b1, bufB);
    k_gemm<<<(NN + TMR - 1) / TMR, 256, 0, stream>>>(bufB, W2, dinv, Gb, NN);
    k_gather<<<(NN + 3) / 4, 256, 0, stream>>>(Gb, coff, csrc, dinv, b2, bufB);

    k_poolfin<<<NG, 256, 0, stream>>>(bufB, bt, Wl, bl, (float*)d_out);
}